// Round 4
// baseline (285.952 us; speedup 1.0000x reference)
//
#include <hip/hip_runtime.h>
#include <hip/hip_cooperative_groups.h>

namespace cg = cooperative_groups;

#define N 4096
#define IN_DIM 6
#define HID 32
#define HEADS1 4
#define D1 (HEADS1*HID)   // 128
#define OUT_DIM 64
#define MAXNB 192         // Binomial(4096,0.01): mean ~41, std 6.4 -> 192 is >20 sigma
#define GRIDC 512
#define ROWS 8            // rows per block per stage (GRIDC*ROWS == N)

// ===================== cooperative single-kernel path =====================
// 3 stages, 2 grid syncs, zero kernel boundaries. launch_bounds(256,4) caps
// VGPR at 128 -> 4 blocks/CU capable; grid 512 needs only 2/CU (2x margin).
__global__ __launch_bounds__(256, 4) void kfused(
    const float* __restrict__ x,
    const float* __restrict__ adj,
    const float* __restrict__ W1,
    const float* __restrict__ a_src1,
    const float* __restrict__ a_dst1,
    const float* __restrict__ b1,
    const float* __restrict__ W2,
    const float* __restrict__ a_src2,
    const float* __restrict__ a_dst2,
    const float* __restrict__ b2v,
    float* __restrict__ hpre,  float* __restrict__ es1, float* __restrict__ ed1,
    float* __restrict__ h2pre, float* __restrict__ es2, float* __restrict__ ed2,
    int* __restrict__ cnt,     int* __restrict__ idxg,  float* __restrict__ out)
{
    cg::grid_group grid = cg::this_grid();
    int t   = threadIdx.x;          // 0..255
    int blk = blockIdx.x;

    // ---------------- Stage A: hpre / es1 / ed1 (2 rows per iteration) ----------------
    {
        __shared__ float xs[2][IN_DIM];
        int r2 = t >> 7;            // row within pair
        int tt = t & 127;           // feature index
        for (int pr = 0; pr < ROWS/2; ++pr) {
            int i = blk*ROWS + pr*2 + r2;
            if (tt < IN_DIM) xs[r2][tt] = x[i*IN_DIM + tt];
            __syncthreads();
            float acc = 0.f;
            #pragma unroll
            for (int k = 0; k < IN_DIM; ++k)
                acc += xs[r2][k] * W1[k*D1 + tt];
            hpre[(size_t)i*D1 + tt] = acc;
            float ps = acc * a_src1[tt];
            float pd = acc * a_dst1[tt];
            #pragma unroll
            for (int off = 16; off >= 1; off >>= 1) {   // xor<32 stays in 32-lane head group
                ps += __shfl_xor(ps, off, 64);
                pd += __shfl_xor(pd, off, 64);
            }
            if ((tt & 31) == 0) {
                int h = tt >> 5;
                es1[i*HEADS1 + h] = ps;
                ed1[i*HEADS1 + h] = pd;
            }
            __syncthreads();        // xs reuse
        }
    }
    grid.sync();

    // ------- Stage B: scan + softmax + aggregate + ELU + W2, rows pipelined -------
    {
        __shared__ int   cS;
        __shared__ int   js[MAXNB];
        __shared__ float lg[HEADS1][MAXNB];
        __shared__ float esiS[HEADS1];
        __shared__ float part[D1];
        __shared__ float h1s[D1];
        __shared__ float p2s[256];

        // prefetch row 0's adjacency (16 KB: 4 float4 per thread)
        const float4* row0 = (const float4*)(adj + (size_t)(blk*ROWS) * N);
        float4 v0 = row0[t], v1 = row0[t+256], v2 = row0[t+512], v3 = row0[t+768];

        for (int pr = 0; pr < ROWS; ++pr) {
            int i = blk*ROWS + pr;
            if (t == 0) cS = 0;
            if (t < HEADS1) esiS[t] = es1[i*HEADS1 + t];
            __syncthreads();

            // scan: 16 candidates per thread, already in registers
            {
                float4 vv[4] = {v0, v1, v2, v3};
                #pragma unroll
                for (int ch = 0; ch < 4; ++ch) {
                    float ff[4] = {vv[ch].x, vv[ch].y, vv[ch].z, vv[ch].w};
                    #pragma unroll
                    for (int q = 0; q < 4; ++q) {
                        int j = (t + 256*ch)*4 + q;
                        if (ff[q] > 0.f || j == i) {
                            int p = atomicAdd(&cS, 1);
                            if (p < MAXNB) js[p] = j;
                        }
                    }
                }
            }
            __syncthreads();
            int c = min(cS, MAXNB);

            // prefetch NEXT row's adjacency: its HBM latency hides under this row
            if (pr + 1 < ROWS) {
                const float4* rn = (const float4*)(adj + (size_t)(i+1) * N);
                v0 = rn[t]; v1 = rn[t+256]; v2 = rn[t+512]; v3 = rn[t+768];
            }

            // logits (one thread per neighbor, all gathers concurrent) + CSR persist
            if (t < c) {
                int j = js[t];
                float4 e4 = ((const float4*)ed1)[j];   // ed1 is [N][4], 16B aligned
                float l0 = esiS[0] + e4.x, l1 = esiS[1] + e4.y,
                      l2 = esiS[2] + e4.z, l3 = esiS[3] + e4.w;
                lg[0][t] = (l0 > 0.f) ? l0 : 0.2f*l0;
                lg[1][t] = (l1 > 0.f) ? l1 : 0.2f*l1;
                lg[2][t] = (l2 > 0.f) ? l2 : 0.2f*l2;
                lg[3][t] = (l3 > 0.f) ? l3 : 0.2f*l3;
                idxg[i*MAXNB + t] = j;
            }
            if (t == 0) cnt[i] = c;
            __syncthreads();

            // in-register softmax stats per 32-lane half-wave (head-consistent)
            int g = t >> 7, tt = t & 127, hh = tt >> 5, hl = t & 31;
            float m = -1e30f;
            for (int p = hl; p < c; p += 32) m = fmaxf(m, lg[hh][p]);
            #pragma unroll
            for (int off = 16; off >= 1; off >>= 1) m = fmaxf(m, __shfl_xor(m, off, 64));
            float s = 0.f;
            for (int p = hl; p < c; p += 32) s += __expf(lg[hh][p] - m);
            #pragma unroll
            for (int off = 16; off >= 1; off >>= 1) s += __shfl_xor(s, off, 64);
            float inv = 1.f / s;

            // aggregate: 2-way p-split, 4x unroll, exp on the fly
            float acc = 0.f;
            int p = g;
            for (; p + 6 < c; p += 8) {
                int   j0 = js[p],   j1 = js[p+2], j2 = js[p+4], j3 = js[p+6];
                float w0 = __expf(lg[hh][p]   - m), w1 = __expf(lg[hh][p+2] - m),
                      w2 = __expf(lg[hh][p+4] - m), w3 = __expf(lg[hh][p+6] - m);
                float x0 = hpre[(size_t)j0*D1 + tt];
                float x1 = hpre[(size_t)j1*D1 + tt];
                float x2 = hpre[(size_t)j2*D1 + tt];
                float x3 = hpre[(size_t)j3*D1 + tt];
                acc += w0*x0 + w1*x1 + w2*x2 + w3*x3;
            }
            for (; p < c; p += 2)
                acc += __expf(lg[hh][p] - m) * hpre[(size_t)js[p]*D1 + tt];
            if (g == 1) part[tt] = acc;
            __syncthreads();
            if (g == 0) {
                acc += part[tt];
                float val = acc * inv + b1[tt];
                h1s[tt] = (val > 0.f) ? val : expm1f(val);   // ELU (alpha=1)
            }
            __syncthreads();

            // layer-2 pre: h2 = h1s @ W2 (4 partials per output column)
            int o = t & 63, q = t >> 6;
            float pa = 0.f;
            #pragma unroll
            for (int k = 0; k < 32; ++k) {
                int kk = q*32 + k;
                pa += h1s[kk] * W2[kk*OUT_DIM + o];
            }
            p2s[t] = pa;
            __syncthreads();
            if (t < 64) {
                float h2 = p2s[t] + p2s[t+64] + p2s[t+128] + p2s[t+192];
                h2pre[(size_t)i*OUT_DIM + t] = h2;
                float ps = h2 * a_src2[t];
                float pd = h2 * a_dst2[t];
                #pragma unroll
                for (int off = 32; off >= 1; off >>= 1) {
                    ps += __shfl_xor(ps, off, 64);
                    pd += __shfl_xor(pd, off, 64);
                }
                if (t == 0) { es2[i] = ps; ed2[i] = pd; }
            }
            __syncthreads();        // LDS reuse for next row
        }
    }
    grid.sync();

    // ---------------- Stage C: layer-2 softmax + aggregate ----------------
    {
        __shared__ int   jsC[MAXNB];
        __shared__ float al[MAXNB];
        __shared__ float partC[3][OUT_DIM];
        for (int pr = 0; pr < ROWS; ++pr) {
            int i = blk*ROWS + pr;
            int c = cnt[i];
            float esi = es2[i];
            if (t < c) {            // one thread per neighbor
                int j = idxg[i*MAXNB + t];
                jsC[t] = j;
                float l = esi + ed2[j];
                al[t] = (l > 0.f) ? l : 0.2f*l;
            }
            __syncthreads();
            int l6 = t & 63;
            float m = -1e30f;
            for (int p = l6; p < c; p += 64) m = fmaxf(m, al[p]);
            #pragma unroll
            for (int off = 32; off >= 1; off >>= 1) m = fmaxf(m, __shfl_xor(m, off, 64));
            float s = 0.f;
            for (int p = l6; p < c; p += 64) s += __expf(al[p] - m);
            #pragma unroll
            for (int off = 32; off >= 1; off >>= 1) s += __shfl_xor(s, off, 64);
            float inv = 1.f / s;
            int g = t >> 6, o = l6;
            float acc = 0.f;
            int p = g;
            for (; p + 12 < c; p += 16) {
                int   j0 = jsC[p],  j1 = jsC[p+4], j2 = jsC[p+8], j3 = jsC[p+12];
                float w0 = __expf(al[p]    - m), w1 = __expf(al[p+4]  - m),
                      w2 = __expf(al[p+8]  - m), w3 = __expf(al[p+12] - m);
                float x0 = h2pre[(size_t)j0*OUT_DIM + o];
                float x1 = h2pre[(size_t)j1*OUT_DIM + o];
                float x2 = h2pre[(size_t)j2*OUT_DIM + o];
                float x3 = h2pre[(size_t)j3*OUT_DIM + o];
                acc += w0*x0 + w1*x1 + w2*x2 + w3*x3;
            }
            for (; p < c; p += 4)
                acc += __expf(al[p] - m) * h2pre[(size_t)jsC[p]*OUT_DIM + o];
            if (g) partC[g-1][o] = acc;
            __syncthreads();
            if (g == 0)
                out[(size_t)i*OUT_DIM + o] =
                    (acc + partC[0][o] + partC[1][o] + partC[2][o]) * inv + b2v[o];
            __syncthreads();        // LDS reuse for next row
        }
    }
}

// ===================== fallback path (round-2 kernels, known-passing) =====================
__global__ void kA_fb(const float* __restrict__ x, const float* __restrict__ W1,
                      const float* __restrict__ a_src1, const float* __restrict__ a_dst1,
                      float* __restrict__ hpre, float* __restrict__ es1, float* __restrict__ ed1) {
    int t  = threadIdx.x;
    int r  = t >> 7;
    int tt = t & 127;
    int i  = blockIdx.x * 2 + r;
    __shared__ float xs[2][IN_DIM];
    if (tt < IN_DIM) xs[r][tt] = x[i*IN_DIM + tt];
    __syncthreads();
    float acc = 0.f;
    #pragma unroll
    for (int k = 0; k < IN_DIM; ++k) acc += xs[r][k] * W1[k*D1 + tt];
    hpre[(size_t)i*D1 + tt] = acc;
    float ps = acc * a_src1[tt];
    float pd = acc * a_dst1[tt];
    #pragma unroll
    for (int off = 16; off >= 1; off >>= 1) {
        ps += __shfl_xor(ps, off, 64);
        pd += __shfl_xor(pd, off, 64);
    }
    if ((tt & 31) == 0) {
        int h = tt >> 5;
        es1[i*HEADS1 + h] = ps;
        ed1[i*HEADS1 + h] = pd;
    }
}

__global__ __launch_bounds__(512) void kB_fb(
                   const float* __restrict__ adj, const float* __restrict__ hpre,
                   const float* __restrict__ es1, const float* __restrict__ ed1,
                   const float* __restrict__ b1,  const float* __restrict__ W2,
                   const float* __restrict__ a_src2, const float* __restrict__ a_dst2,
                   int* __restrict__ cnt, int* __restrict__ idxg,
                   float* __restrict__ h2pre, float* __restrict__ es2, float* __restrict__ ed2) {
    int i = blockIdx.x;
    int t = threadIdx.x;
    __shared__ int   cL;
    __shared__ int   js[MAXNB];
    __shared__ float lg[HEADS1][MAXNB];
    __shared__ float esi[HEADS1];
    __shared__ float sinv[HEADS1];
    __shared__ float part[3][D1];
    __shared__ float h1s[D1];
    __shared__ float p2s[512];
    if (t == 0) cL = 0;
    if (t < HEADS1) esi[t] = es1[i*HEADS1 + t];
    __syncthreads();
    const float4* row = (const float4*)(adj + (size_t)i * N);
    float4 v0 = row[t];
    float4 v1 = row[t + 512];
    float f[8] = {v0.x, v0.y, v0.z, v0.w, v1.x, v1.y, v1.z, v1.w};
    #pragma unroll
    for (int q = 0; q < 8; ++q) {
        int j = (q < 4) ? (t*4 + q) : (2048 + t*4 + (q - 4));
        if (f[q] > 0.f || j == i) {
            int p = atomicAdd(&cL, 1);
            if (p < MAXNB) js[p] = j;
        }
    }
    __syncthreads();
    int c = min(cL, MAXNB);
    if (t < c) {
        int j = js[t];
        float4 e4 = ((const float4*)ed1)[j];
        float l0 = esi[0] + e4.x, l1 = esi[1] + e4.y, l2 = esi[2] + e4.z, l3 = esi[3] + e4.w;
        lg[0][t] = (l0 > 0.f) ? l0 : 0.2f*l0;
        lg[1][t] = (l1 > 0.f) ? l1 : 0.2f*l1;
        lg[2][t] = (l2 > 0.f) ? l2 : 0.2f*l2;
        lg[3][t] = (l3 > 0.f) ? l3 : 0.2f*l3;
    }
    if (t >= 256) {
        int p = t - 256;
        if (p == 0) cnt[i] = c;
        if (p < c) idxg[i*MAXNB + p] = js[p];
    }
    __syncthreads();
    if (t < 256) {
        int h = t >> 6, l = t & 63;
        float m = -1e30f;
        for (int p = l; p < c; p += 64) m = fmaxf(m, lg[h][p]);
        #pragma unroll
        for (int off = 32; off >= 1; off >>= 1) m = fmaxf(m, __shfl_xor(m, off, 64));
        float s = 0.f;
        for (int p = l; p < c; p += 64) {
            float e = __expf(lg[h][p] - m);
            lg[h][p] = e;
            s += e;
        }
        #pragma unroll
        for (int off = 32; off >= 1; off >>= 1) s += __shfl_xor(s, off, 64);
        if (l == 0) sinv[h] = 1.f / s;
    }
    __syncthreads();
    int g = t >> 7, tt = t & 127, hh = tt >> 5;
    float acc = 0.f;
    int p = g;
    for (; p + 12 < c; p += 16) {
        int   j0 = js[p],      j1 = js[p+4],   j2 = js[p+8],   j3 = js[p+12];
        float w0 = lg[hh][p],  w1 = lg[hh][p+4], w2 = lg[hh][p+8], w3 = lg[hh][p+12];
        float x0 = hpre[(size_t)j0*D1 + tt];
        float x1 = hpre[(size_t)j1*D1 + tt];
        float x2 = hpre[(size_t)j2*D1 + tt];
        float x3 = hpre[(size_t)j3*D1 + tt];
        acc += w0*x0 + w1*x1 + w2*x2 + w3*x3;
    }
    for (; p < c; p += 4)
        acc += lg[hh][p] * hpre[(size_t)js[p]*D1 + tt];
    if (g) part[g-1][tt] = acc;
    __syncthreads();
    if (g == 0) {
        acc += part[0][tt] + part[1][tt] + part[2][tt];
        float val = acc * sinv[hh] + b1[tt];
        h1s[tt] = (val > 0.f) ? val : expm1f(val);
    }
    __syncthreads();
    int o = t & 63, q = t >> 6;
    float pa = 0.f;
    #pragma unroll
    for (int k = 0; k < 16; ++k) {
        int kk = q*16 + k;
        pa += h1s[kk] * W2[kk*OUT_DIM + o];
    }
    p2s[t] = pa;
    __syncthreads();
    if (t < 64) {
        float h2 = 0.f;
        #pragma unroll
        for (int qq = 0; qq < 8; ++qq) h2 += p2s[t + 64*qq];
        h2pre[(size_t)i*OUT_DIM + t] = h2;
        float ps = h2 * a_src2[t];
        float pd = h2 * a_dst2[t];
        #pragma unroll
        for (int off = 32; off >= 1; off >>= 1) {
            ps += __shfl_xor(ps, off, 64);
            pd += __shfl_xor(pd, off, 64);
        }
        if (t == 0) { es2[i] = ps; ed2[i] = pd; }
    }
}

__global__ __launch_bounds__(256) void kC_fb(
                   const float* __restrict__ h2pre, const float* __restrict__ es2,
                   const float* __restrict__ ed2, const int* __restrict__ cnt,
                   const int* __restrict__ idxg, const float* __restrict__ b2v,
                   float* __restrict__ out) {
    int i = blockIdx.x;
    int t = threadIdx.x;
    int c = cnt[i];
    __shared__ int   js[MAXNB];
    __shared__ float al[MAXNB];
    __shared__ float sinv_s;
    __shared__ float part[3][OUT_DIM];
    float esi = es2[i];
    if (t < c) {
        int j = idxg[i*MAXNB + t];
        js[t] = j;
        float l = esi + ed2[j];
        al[t] = (l > 0.f) ? l : 0.2f*l;
    }
    __syncthreads();
    if (t < 64) {
        float m = -1e30f;
        for (int p = t; p < c; p += 64) m = fmaxf(m, al[p]);
        #pragma unroll
        for (int off = 32; off >= 1; off >>= 1) m = fmaxf(m, __shfl_xor(m, off, 64));
        float s = 0.f;
        for (int p = t; p < c; p += 64) {
            float e = __expf(al[p] - m);
            al[p] = e;
            s += e;
        }
        #pragma unroll
        for (int off = 32; off >= 1; off >>= 1) s += __shfl_xor(s, off, 64);
        if (t == 0) sinv_s = 1.f / s;
    }
    __syncthreads();
    int g = t >> 6, o = t & 63;
    float acc = 0.f;
    int p = g;
    for (; p + 12 < c; p += 16) {
        int   j0 = js[p],    j1 = js[p+4],  j2 = js[p+8],  j3 = js[p+12];
        float w0 = al[p],    w1 = al[p+4],  w2 = al[p+8],  w3 = al[p+12];
        float x0 = h2pre[(size_t)j0*OUT_DIM + o];
        float x1 = h2pre[(size_t)j1*OUT_DIM + o];
        float x2 = h2pre[(size_t)j2*OUT_DIM + o];
        float x3 = h2pre[(size_t)j3*OUT_DIM + o];
        acc += w0*x0 + w1*x1 + w2*x2 + w3*x3;
    }
    for (; p < c; p += 4)
        acc += al[p] * h2pre[(size_t)js[p]*OUT_DIM + o];
    if (g) part[g-1][o] = acc;
    __syncthreads();
    if (g == 0) {
        acc += part[0][o] + part[1][o] + part[2][o];
        out[(size_t)i*OUT_DIM + o] = acc * sinv_s + b2v[o];
    }
}

extern "C" void kernel_launch(void* const* d_in, const int* in_sizes, int n_in,
                              void* d_out, int out_size, void* d_ws, size_t ws_size,
                              hipStream_t stream) {
    const float* x      = (const float*)d_in[0];
    const float* adj    = (const float*)d_in[1];
    const float* W1     = (const float*)d_in[2];
    const float* a_src1 = (const float*)d_in[3];
    const float* a_dst1 = (const float*)d_in[4];
    const float* b1     = (const float*)d_in[5];
    const float* W2     = (const float*)d_in[6];
    const float* a_src2 = (const float*)d_in[7];
    const float* a_dst2 = (const float*)d_in[8];
    const float* b2v    = (const float*)d_in[9];
    float* out = (float*)d_out;

    float* ws    = (float*)d_ws;
    float* hpre  = ws;                        // N*128
    float* h2pre = hpre  + (size_t)N*D1;      // N*64
    float* es1   = h2pre + (size_t)N*OUT_DIM; // N*4
    float* ed1   = es1   + (size_t)N*HEADS1;  // N*4  (16B-aligned for float4 loads)
    float* es2   = ed1   + (size_t)N*HEADS1;  // N
    float* ed2   = es2   + N;                 // N
    int*   cnt   = (int*)(ed2 + N);           // N
    int*   idxg  = cnt + N;                   // N*MAXNB

    // gate the cooperative path: device support + runtime-computed residency
    static int use_coop = -1;
    if (use_coop < 0) {
        int dev = 0, attr = 0, ncu = 0, perCU = 0;
        hipGetDevice(&dev);
        hipDeviceGetAttribute(&attr, hipDeviceAttributeCooperativeLaunch, dev);
        hipDeviceGetAttribute(&ncu, hipDeviceAttributeMultiprocessorCount, dev);
        hipOccupancyMaxActiveBlocksPerMultiprocessor(&perCU, kfused, 256, 0);
        use_coop = (attr && (long)perCU * ncu >= GRIDC) ? 1 : 0;
    }

    if (use_coop) {
        void* args[] = {
            (void*)&x, (void*)&adj, (void*)&W1, (void*)&a_src1, (void*)&a_dst1,
            (void*)&b1, (void*)&W2, (void*)&a_src2, (void*)&a_dst2, (void*)&b2v,
            (void*)&hpre, (void*)&es1, (void*)&ed1,
            (void*)&h2pre, (void*)&es2, (void*)&ed2,
            (void*)&cnt, (void*)&idxg, (void*)&out
        };
        hipError_t e = hipLaunchCooperativeKernel((void*)kfused, dim3(GRIDC), dim3(256),
                                                  args, 0, stream);
        if (e == hipSuccess) return;
        use_coop = 0;   // launch rejected -> permanent fallback
    }

    kA_fb<<<N/2, 256, 0, stream>>>(x, W1, a_src1, a_dst1, hpre, es1, ed1);
    kB_fb<<<N,   512, 0, stream>>>(adj, hpre, es1, ed1, b1, W2, a_src2, a_dst2,
                                   cnt, idxg, h2pre, es2, ed2);
    kC_fb<<<N,   256, 0, stream>>>(h2pre, es2, ed2, cnt, idxg, b2v, out);
}

// Round 6
// 147.414 us; speedup vs baseline: 1.9398x; 1.9398x over previous
//
#include <hip/hip_runtime.h>

#define N 4096
#define IN_DIM 6
#define HEADS1 4
#define D1 128            // HEADS1*32
#define OUT_DIM 64
#define MAXNB 192         // Binomial(4096,0.01): mean ~41, std 6.4 -> >20 sigma

// Intra-wave LDS ordering fence: all LDS here is wave-private, so a full
// __syncthreads() is overkill; wait out the DS queue and pin the scheduler.
#define WFENCE() do { asm volatile("s_waitcnt lgkmcnt(0)" ::: "memory"); \
                      __builtin_amdgcn_sched_barrier(0); } while (0)

__device__ __forceinline__ float lrelu(float v) { return v > 0.f ? v : 0.2f * v; }
__device__ __forceinline__ float selh(float4 v, int h) {
    return (h == 0) ? v.x : (h == 1) ? v.y : (h == 2) ? v.z : v.w;
}

// ---------------- kA: wave-per-row hpre/es1/ed1 (+ one-time W2 transpose) ----------------
// grid N/4, block 256. No LDS, no barriers. Lane l owns features 2l, 2l+1 (same head).
__global__ __launch_bounds__(256) void kA(
    const float* __restrict__ x,  const float* __restrict__ W1,
    const float* __restrict__ a_src1, const float* __restrict__ a_dst1,
    const float* __restrict__ W2,
    float* __restrict__ hpre, float* __restrict__ es1, float* __restrict__ ed1,
    float* __restrict__ W2T)
{
    int w = threadIdx.x >> 6, l = threadIdx.x & 63;
    int i = blockIdx.x * 4 + w;

    float xv[IN_DIM];
    #pragma unroll
    for (int k = 0; k < IN_DIM; ++k) xv[k] = x[i*IN_DIM + k];   // wave-broadcast loads

    float a0 = 0.f, a1 = 0.f;
    #pragma unroll
    for (int k = 0; k < IN_DIM; ++k) {
        float2 wv = ((const float2*)W1)[k*64 + l];
        a0 += xv[k] * wv.x;
        a1 += xv[k] * wv.y;
    }
    float2 hv; hv.x = a0; hv.y = a1;
    ((float2*)hpre)[(size_t)i*64 + l] = hv;

    float2 asv = ((const float2*)a_src1)[l];
    float2 adv = ((const float2*)a_dst1)[l];
    float ps = a0*asv.x + a1*asv.y;
    float pd = a0*adv.x + a1*adv.y;
    #pragma unroll
    for (int off = 8; off >= 1; off >>= 1) {   // reduce within 16-lane head group
        ps += __shfl_xor(ps, off, 64);
        pd += __shfl_xor(pd, off, 64);
    }
    if ((l & 15) == 0) {
        int h = l >> 4;
        es1[i*HEADS1 + h] = ps;
        ed1[i*HEADS1 + h] = pd;
    }

    // one-time W2 transpose into workspace: W2T[o][k] = W2[k][o]
    if (blockIdx.x == 0) {
        for (int idx = threadIdx.x; idx < D1*OUT_DIM; idx += 256) {
            int k = idx >> 6, o = idx & 63;
            W2T[o*D1 + k] = W2[idx];
        }
    }
}

// ---------------- kB: wave-per-row fused layer-1 + W2 projection ----------------
// grid N/4, block 256, ZERO __syncthreads. Per wave: chunked full-row scan with
// ballot prefix compaction, one-round logit gather, in-register softmax stats,
// float2 aggregate, ELU, W2T matvec, es2/ed2.
__global__ __launch_bounds__(256, 4) void kB(
    const float* __restrict__ adj,  const float* __restrict__ hpre,
    const float* __restrict__ es1,  const float* __restrict__ ed1,
    const float* __restrict__ b1,   const float* __restrict__ W2T,
    const float* __restrict__ a_src2, const float* __restrict__ a_dst2,
    int* __restrict__ cnt, int* __restrict__ idxg,
    float* __restrict__ h2pre, float* __restrict__ es2, float* __restrict__ ed2)
{
    __shared__ int   jsS[4][MAXNB];
    __shared__ float lgS[4][HEADS1][MAXNB];
    __shared__ float h1S[4][D1];
    int w = threadIdx.x >> 6, l = threadIdx.x & 63;
    int i = blockIdx.x * 4 + w;
    int*   js  = jsS[w];
    float (*lg)[MAXNB] = lgS[w];
    float* h1s = h1S[w];

    // ---- scan FULL row (4096 cols = 16 float4/lane) in 4 chunks with prefetch ----
    const float4* row = (const float4*)(adj + (size_t)i * N);   // 1024 float4
    unsigned long long lanem = (1ull << l) - 1ull;
    int base = 0;
    float4 buf[4];
    #pragma unroll
    for (int u = 0; u < 4; ++u) buf[u] = row[l + 64*u];
    #pragma unroll
    for (int ch = 0; ch < 4; ++ch) {
        float4 nbuf[4];
        if (ch < 3) {
            #pragma unroll
            for (int u = 0; u < 4; ++u) nbuf[u] = row[l + 64*u + 256*(ch+1)];
        }
        #pragma unroll
        for (int u = 0; u < 4; ++u) {
            float fe[4] = {buf[u].x, buf[u].y, buf[u].z, buf[u].w};
            #pragma unroll
            for (int e = 0; e < 4; ++e) {
                int j = (256*ch + 64*u + l)*4 + e;
                bool pred = (fe[e] > 0.f) || (j == i);
                unsigned long long mask = __ballot(pred);
                if (pred) {
                    int pos = base + (int)__popcll(mask & lanem);
                    if (pos < MAXNB) js[pos] = j;
                }
                base += (int)__popcll(mask);
            }
        }
        if (ch < 3) {
            #pragma unroll
            for (int u = 0; u < 4; ++u) buf[u] = nbuf[u];
        }
    }
    int c = min(base, MAXNB);
    if (l == 0) cnt[i] = c;
    WFENCE();                          // js[] visible across lanes

    // ---- logits: one lane per neighbor (1-3 rounds), persist CSR ----
    float4 esv = ((const float4*)es1)[i];
    float4 lr0, lr1, lr2;
    lr0.x = lr0.y = lr0.z = lr0.w = -1e30f; lr1 = lr0; lr2 = lr0;
    if (l < c) {
        int j = js[l];
        float4 e4 = ((const float4*)ed1)[j];
        lr0.x = lrelu(esv.x + e4.x); lr0.y = lrelu(esv.y + e4.y);
        lr0.z = lrelu(esv.z + e4.z); lr0.w = lrelu(esv.w + e4.w);
        lg[0][l] = lr0.x; lg[1][l] = lr0.y; lg[2][l] = lr0.z; lg[3][l] = lr0.w;
        idxg[i*MAXNB + l] = j;
    }
    if (l + 64 < c) {
        int p = l + 64, j = js[p];
        float4 e4 = ((const float4*)ed1)[j];
        lr1.x = lrelu(esv.x + e4.x); lr1.y = lrelu(esv.y + e4.y);
        lr1.z = lrelu(esv.z + e4.z); lr1.w = lrelu(esv.w + e4.w);
        lg[0][p] = lr1.x; lg[1][p] = lr1.y; lg[2][p] = lr1.z; lg[3][p] = lr1.w;
        idxg[i*MAXNB + p] = j;
    }
    if (l + 128 < c) {
        int p = l + 128, j = js[p];
        float4 e4 = ((const float4*)ed1)[j];
        lr2.x = lrelu(esv.x + e4.x); lr2.y = lrelu(esv.y + e4.y);
        lr2.z = lrelu(esv.z + e4.z); lr2.w = lrelu(esv.w + e4.w);
        lg[0][p] = lr2.x; lg[1][p] = lr2.y; lg[2][p] = lr2.z; lg[3][p] = lr2.w;
        idxg[i*MAXNB + p] = j;
    }

    // ---- softmax stats fully in registers (per-head wave reduce) ----
    float4 mm;
    mm.x = fmaxf(lr0.x, fmaxf(lr1.x, lr2.x));
    mm.y = fmaxf(lr0.y, fmaxf(lr1.y, lr2.y));
    mm.z = fmaxf(lr0.z, fmaxf(lr1.z, lr2.z));
    mm.w = fmaxf(lr0.w, fmaxf(lr1.w, lr2.w));
    #pragma unroll
    for (int off = 32; off >= 1; off >>= 1) {
        mm.x = fmaxf(mm.x, __shfl_xor(mm.x, off, 64));
        mm.y = fmaxf(mm.y, __shfl_xor(mm.y, off, 64));
        mm.z = fmaxf(mm.z, __shfl_xor(mm.z, off, 64));
        mm.w = fmaxf(mm.w, __shfl_xor(mm.w, off, 64));
    }
    float4 ss;   // exp(-1e30 - m) underflows to 0 for inactive slots
    ss.x = __expf(lr0.x-mm.x) + __expf(lr1.x-mm.x) + __expf(lr2.x-mm.x);
    ss.y = __expf(lr0.y-mm.y) + __expf(lr1.y-mm.y) + __expf(lr2.y-mm.y);
    ss.z = __expf(lr0.z-mm.z) + __expf(lr1.z-mm.z) + __expf(lr2.z-mm.z);
    ss.w = __expf(lr0.w-mm.w) + __expf(lr1.w-mm.w) + __expf(lr2.w-mm.w);
    #pragma unroll
    for (int off = 32; off >= 1; off >>= 1) {
        ss.x += __shfl_xor(ss.x, off, 64);
        ss.y += __shfl_xor(ss.y, off, 64);
        ss.z += __shfl_xor(ss.z, off, 64);
        ss.w += __shfl_xor(ss.w, off, 64);
    }
    WFENCE();                          // lg[] visible across lanes

    // ---- aggregate: lane l owns features 2l,2l+1 (head l>>4), 8x unrolled ----
    int hl = l >> 4;
    float m   = selh(mm, hl);
    float inv = 1.f / selh(ss, hl);
    const float2* hp2 = (const float2*)hpre;
    float ax = 0.f, ay = 0.f;
    int p = 0;
    for (; p + 8 <= c; p += 8) {
        int   jj[8]; float ww[8];
        #pragma unroll
        for (int u = 0; u < 8; ++u) jj[u] = js[p+u];
        #pragma unroll
        for (int u = 0; u < 8; ++u) ww[u] = __expf(lg[hl][p+u] - m);
        #pragma unroll
        for (int u = 0; u < 8; ++u) {
            float2 v = hp2[(size_t)jj[u]*64 + l];
            ax += ww[u]*v.x; ay += ww[u]*v.y;
        }
    }
    for (; p < c; ++p) {
        float wv = __expf(lg[hl][p] - m);
        float2 v = hp2[(size_t)js[p]*64 + l];
        ax += wv*v.x; ay += wv*v.y;
    }
    float2 bv = ((const float2*)b1)[l];
    float v0 = ax*inv + bv.x, v1 = ay*inv + bv.y;
    v0 = (v0 > 0.f) ? v0 : expm1f(v0);   // ELU (alpha=1)
    v1 = (v1 > 0.f) ? v1 : expm1f(v1);
    { float2 hw; hw.x = v0; hw.y = v1; *(float2*)(h1s + 2*l) = hw; }
    WFENCE();                          // h1s[] visible across lanes

    // ---- layer-2 pre: h2[o=l] = h1s . W2T[l][:], lane-private float4 row ----
    const float4* wrow = (const float4*)(W2T + (size_t)l*D1);
    float h2 = 0.f;
    #pragma unroll 8
    for (int k4 = 0; k4 < 32; ++k4) {
        float4 wv = wrow[k4];
        float4 hvv = *(const float4*)(h1s + k4*4);   // broadcast LDS read
        h2 += wv.x*hvv.x + wv.y*hvv.y + wv.z*hvv.z + wv.w*hvv.w;
    }
    h2pre[(size_t)i*OUT_DIM + l] = h2;
    float ps = h2 * a_src2[l];
    float pd = h2 * a_dst2[l];
    #pragma unroll
    for (int off = 32; off >= 1; off >>= 1) {
        ps += __shfl_xor(ps, off, 64);
        pd += __shfl_xor(pd, off, 64);
    }
    if (l == 0) { es2[i] = ps; ed2[i] = pd; }
}

// ---------------- kC: wave-per-row layer-2 softmax + aggregate ----------------
// grid N/4, block 256, zero __syncthreads.
__global__ __launch_bounds__(256, 6) void kC(
    const float* __restrict__ h2pre, const float* __restrict__ es2,
    const float* __restrict__ ed2,   const int* __restrict__ cnt,
    const int* __restrict__ idxg,    const float* __restrict__ b2v,
    float* __restrict__ out)
{
    __shared__ int   jsS[4][MAXNB];
    __shared__ float alS[4][MAXNB];
    int w = threadIdx.x >> 6, l = threadIdx.x & 63;
    int i = blockIdx.x * 4 + w;
    int*   js = jsS[w];
    float* al = alS[w];
    int c = cnt[i];
    float esi = es2[i];

    float l0 = -1e30f, l1 = -1e30f, l2 = -1e30f;
    if (l < c) {
        int j = idxg[i*MAXNB + l];            js[l] = j;
        float v = lrelu(esi + ed2[j]);        al[l] = v;  l0 = v;
    }
    if (l + 64 < c) {
        int p = l + 64, j = idxg[i*MAXNB + p]; js[p] = j;
        float v = lrelu(esi + ed2[j]);         al[p] = v;  l1 = v;
    }
    if (l + 128 < c) {
        int p = l + 128, j = idxg[i*MAXNB + p]; js[p] = j;
        float v = lrelu(esi + ed2[j]);          al[p] = v;  l2 = v;
    }
    float m = fmaxf(l0, fmaxf(l1, l2));
    #pragma unroll
    for (int off = 32; off >= 1; off >>= 1) m = fmaxf(m, __shfl_xor(m, off, 64));
    float s = __expf(l0-m) + __expf(l1-m) + __expf(l2-m);
    #pragma unroll
    for (int off = 32; off >= 1; off >>= 1) s += __shfl_xor(s, off, 64);
    float inv = 1.f / s;
    WFENCE();                          // js/al visible across lanes

    float acc = 0.f;
    int p = 0;
    for (; p + 8 <= c; p += 8) {
        int   jj[8]; float ww[8];
        #pragma unroll
        for (int u = 0; u < 8; ++u) jj[u] = js[p+u];
        #pragma unroll
        for (int u = 0; u < 8; ++u) ww[u] = __expf(al[p+u] - m);
        #pragma unroll
        for (int u = 0; u < 8; ++u)
            acc += ww[u] * h2pre[(size_t)jj[u]*OUT_DIM + l];
    }
    for (; p < c; ++p)
        acc += __expf(al[p] - m) * h2pre[(size_t)js[p]*OUT_DIM + l];
    out[(size_t)i*OUT_DIM + l] = acc*inv + b2v[l];
}

extern "C" void kernel_launch(void* const* d_in, const int* in_sizes, int n_in,
                              void* d_out, int out_size, void* d_ws, size_t ws_size,
                              hipStream_t stream) {
    const float* x      = (const float*)d_in[0];
    const float* adj    = (const float*)d_in[1];
    const float* W1     = (const float*)d_in[2];
    const float* a_src1 = (const float*)d_in[3];
    const float* a_dst1 = (const float*)d_in[4];
    const float* b1     = (const float*)d_in[5];
    const float* W2     = (const float*)d_in[6];
    const float* a_src2 = (const float*)d_in[7];
    const float* a_dst2 = (const float*)d_in[8];
    const float* b2v    = (const float*)d_in[9];
    float* out = (float*)d_out;

    float* ws    = (float*)d_ws;
    float* hpre  = ws;                         // N*128
    float* h2pre = hpre  + (size_t)N*D1;       // N*64
    float* es1   = h2pre + (size_t)N*OUT_DIM;  // N*4
    float* ed1   = es1   + (size_t)N*HEADS1;   // N*4 (16B-aligned)
    float* es2   = ed1   + (size_t)N*HEADS1;   // N
    float* ed2   = es2   + N;                  // N
    float* W2T   = ed2   + N;                  // 64*128
    int*   cnt   = (int*)(W2T + OUT_DIM*D1);   // N
    int*   idxg  = cnt + N;                    // N*MAXNB

    kA<<<N/4, 256, 0, stream>>>(x, W1, a_src1, a_dst1, W2, hpre, es1, ed1, W2T);
    kB<<<N/4, 256, 0, stream>>>(adj, hpre, es1, ed1, b1, W2T, a_src2, a_dst2,
                                cnt, idxg, h2pre, es2, ed2);
    kC<<<N/4, 256, 0, stream>>>(h2pre, es2, ed2, cnt, idxg, b2v, out);
}

// Round 7
// 144.659 us; speedup vs baseline: 1.9767x; 1.0190x over previous
//
#include <hip/hip_runtime.h>

#define N 4096
#define IN_DIM 6
#define HEADS1 4
#define D1 128            // HEADS1*32
#define OUT_DIM 64
#define MAXNB 192         // Binomial(4096,0.01): mean ~41, std 6.4 -> >20 sigma
#define LGS 200           // lg stride: (p + 8h)%32 puts the 4 head-groups on distinct banks

// Intra-wave LDS ordering fence: all LDS here is wave-private, so a full
// __syncthreads() is overkill; wait out the DS queue and pin the scheduler.
#define WFENCE() do { asm volatile("s_waitcnt lgkmcnt(0)" ::: "memory"); \
                      __builtin_amdgcn_sched_barrier(0); } while (0)

__device__ __forceinline__ float lrelu(float v) { return v > 0.f ? v : 0.2f * v; }
__device__ __forceinline__ float selh(float4 v, int h) {
    return (h == 0) ? v.x : (h == 1) ? v.y : (h == 2) ? v.z : v.w;
}

// ---------------- kA: wave-per-row hpre/es1/ed1 (+ one-time W2 transpose) ----------------
// grid N/4, block 256. No LDS, no barriers. Lane l owns features 2l, 2l+1 (same head).
__global__ __launch_bounds__(256) void kA(
    const float* __restrict__ x,  const float* __restrict__ W1,
    const float* __restrict__ a_src1, const float* __restrict__ a_dst1,
    const float* __restrict__ W2,
    float* __restrict__ hpre, float* __restrict__ es1, float* __restrict__ ed1,
    float* __restrict__ W2T)
{
    int w = threadIdx.x >> 6, l = threadIdx.x & 63;
    int i = blockIdx.x * 4 + w;

    float xv[IN_DIM];
    #pragma unroll
    for (int k = 0; k < IN_DIM; ++k) xv[k] = x[i*IN_DIM + k];   // wave-broadcast loads

    float a0 = 0.f, a1 = 0.f;
    #pragma unroll
    for (int k = 0; k < IN_DIM; ++k) {
        float2 wv = ((const float2*)W1)[k*64 + l];
        a0 += xv[k] * wv.x;
        a1 += xv[k] * wv.y;
    }
    float2 hv; hv.x = a0; hv.y = a1;
    ((float2*)hpre)[(size_t)i*64 + l] = hv;

    float2 asv = ((const float2*)a_src1)[l];
    float2 adv = ((const float2*)a_dst1)[l];
    float ps = a0*asv.x + a1*asv.y;
    float pd = a0*adv.x + a1*adv.y;
    #pragma unroll
    for (int off = 8; off >= 1; off >>= 1) {   // reduce within 16-lane head group
        ps += __shfl_xor(ps, off, 64);
        pd += __shfl_xor(pd, off, 64);
    }
    if ((l & 15) == 0) {
        int h = l >> 4;
        es1[i*HEADS1 + h] = ps;
        ed1[i*HEADS1 + h] = pd;
    }

    // one-time W2 transpose into workspace: W2T[o][k] = W2[k][o]
    if (blockIdx.x == 0) {
        for (int idx = threadIdx.x; idx < D1*OUT_DIM; idx += 256) {
            int k = idx >> 6, o = idx & 63;
            W2T[o*D1 + k] = W2[idx];
        }
    }
}

// ---------------- kB: wave-per-row fused layer-1 + W2 projection ----------------
// grid N/4, block 256, ZERO __syncthreads. Per wave: whole-row scan with ALL 16
// float4 loads issued upfront (16 KB in flight, sched_barrier-pinned), ballot
// prefix compaction, one-round logit gather, in-register softmax stats,
// pre-normalized weights in LDS, float2 aggregate, ELU, W2T matvec, es2/ed2.
__global__ __launch_bounds__(256, 4) void kB(
    const float* __restrict__ adj,  const float* __restrict__ hpre,
    const float* __restrict__ es1,  const float* __restrict__ ed1,
    const float* __restrict__ b1,   const float* __restrict__ W2T,
    const float* __restrict__ a_src2, const float* __restrict__ a_dst2,
    int* __restrict__ cnt, int* __restrict__ idxg,
    float* __restrict__ h2pre, float* __restrict__ es2, float* __restrict__ ed2)
{
    __shared__ int   jsS[4][MAXNB];
    __shared__ float lgS[4][HEADS1][LGS];
    __shared__ float h1S[4][D1];
    int w = threadIdx.x >> 6, l = threadIdx.x & 63;
    int i = blockIdx.x * 4 + w;
    int*   js  = jsS[w];
    float (*lg)[LGS] = lgS[w];
    float* h1s = h1S[w];

    // ---- scan FULL row: all 16 float4/lane issued before any processing ----
    const float4* row = (const float4*)(adj + (size_t)i * N);   // 1024 float4
    float4 buf[16];
    #pragma unroll
    for (int u = 0; u < 16; ++u) buf[u] = row[l + 64*u];
    __builtin_amdgcn_sched_barrier(0);          // keep all 16 loads issued above

    unsigned long long lanem = (1ull << l) - 1ull;
    int base = 0;
    #pragma unroll
    for (int u = 0; u < 16; ++u) {
        float fe[4] = {buf[u].x, buf[u].y, buf[u].z, buf[u].w};
        #pragma unroll
        for (int e = 0; e < 4; ++e) {
            int j = (64*u + l)*4 + e;
            bool pred = (fe[e] > 0.f) || (j == i);
            unsigned long long mask = __ballot(pred);
            if (pred) {
                int pos = base + (int)__popcll(mask & lanem);
                if (pos < MAXNB) js[pos] = j;
            }
            base += (int)__popcll(mask);
        }
    }
    int c = min(base, MAXNB);
    if (l == 0) cnt[i] = c;
    WFENCE();                          // js[] visible across lanes

    // ---- logits: one lane per neighbor (1-3 rounds), persist CSR, regs only ----
    float4 esv = ((const float4*)es1)[i];
    float4 lr0, lr1, lr2;
    lr0.x = lr0.y = lr0.z = lr0.w = -1e30f; lr1 = lr0; lr2 = lr0;
    if (l < c) {
        int j = js[l];
        float4 e4 = ((const float4*)ed1)[j];
        lr0.x = lrelu(esv.x + e4.x); lr0.y = lrelu(esv.y + e4.y);
        lr0.z = lrelu(esv.z + e4.z); lr0.w = lrelu(esv.w + e4.w);
        idxg[i*MAXNB + l] = j;
    }
    if (l + 64 < c) {
        int p = l + 64, j = js[p];
        float4 e4 = ((const float4*)ed1)[j];
        lr1.x = lrelu(esv.x + e4.x); lr1.y = lrelu(esv.y + e4.y);
        lr1.z = lrelu(esv.z + e4.z); lr1.w = lrelu(esv.w + e4.w);
        idxg[i*MAXNB + p] = j;
    }
    if (l + 128 < c) {
        int p = l + 128, j = js[p];
        float4 e4 = ((const float4*)ed1)[j];
        lr2.x = lrelu(esv.x + e4.x); lr2.y = lrelu(esv.y + e4.y);
        lr2.z = lrelu(esv.z + e4.z); lr2.w = lrelu(esv.w + e4.w);
        idxg[i*MAXNB + p] = j;
    }

    // ---- softmax stats fully in registers (per-head wave reduce) ----
    float4 mm;
    mm.x = fmaxf(lr0.x, fmaxf(lr1.x, lr2.x));
    mm.y = fmaxf(lr0.y, fmaxf(lr1.y, lr2.y));
    mm.z = fmaxf(lr0.z, fmaxf(lr1.z, lr2.z));
    mm.w = fmaxf(lr0.w, fmaxf(lr1.w, lr2.w));
    #pragma unroll
    for (int off = 32; off >= 1; off >>= 1) {
        mm.x = fmaxf(mm.x, __shfl_xor(mm.x, off, 64));
        mm.y = fmaxf(mm.y, __shfl_xor(mm.y, off, 64));
        mm.z = fmaxf(mm.z, __shfl_xor(mm.z, off, 64));
        mm.w = fmaxf(mm.w, __shfl_xor(mm.w, off, 64));
    }
    float4 ex0, ex1, ex2;   // exp(-1e30 - m) underflows to 0 for inactive slots
    ex0.x = __expf(lr0.x-mm.x); ex0.y = __expf(lr0.y-mm.y);
    ex0.z = __expf(lr0.z-mm.z); ex0.w = __expf(lr0.w-mm.w);
    ex1.x = __expf(lr1.x-mm.x); ex1.y = __expf(lr1.y-mm.y);
    ex1.z = __expf(lr1.z-mm.z); ex1.w = __expf(lr1.w-mm.w);
    ex2.x = __expf(lr2.x-mm.x); ex2.y = __expf(lr2.y-mm.y);
    ex2.z = __expf(lr2.z-mm.z); ex2.w = __expf(lr2.w-mm.w);
    float4 ss;
    ss.x = ex0.x + ex1.x + ex2.x;
    ss.y = ex0.y + ex1.y + ex2.y;
    ss.z = ex0.z + ex1.z + ex2.z;
    ss.w = ex0.w + ex1.w + ex2.w;
    #pragma unroll
    for (int off = 32; off >= 1; off >>= 1) {
        ss.x += __shfl_xor(ss.x, off, 64);
        ss.y += __shfl_xor(ss.y, off, 64);
        ss.z += __shfl_xor(ss.z, off, 64);
        ss.w += __shfl_xor(ss.w, off, 64);
    }
    // store PRE-NORMALIZED weights: aggregate loop needs no exp and no final inv
    float4 iv; iv.x = 1.f/ss.x; iv.y = 1.f/ss.y; iv.z = 1.f/ss.z; iv.w = 1.f/ss.w;
    lg[0][l]     = ex0.x*iv.x; lg[1][l]     = ex0.y*iv.y;
    lg[2][l]     = ex0.z*iv.z; lg[3][l]     = ex0.w*iv.w;
    lg[0][l+64]  = ex1.x*iv.x; lg[1][l+64]  = ex1.y*iv.y;
    lg[2][l+64]  = ex1.z*iv.z; lg[3][l+64]  = ex1.w*iv.w;
    lg[0][l+128] = ex2.x*iv.x; lg[1][l+128] = ex2.y*iv.y;
    lg[2][l+128] = ex2.z*iv.z; lg[3][l+128] = ex2.w*iv.w;
    WFENCE();                          // lg[] visible across lanes

    // ---- aggregate: lane l owns features 2l,2l+1 (head l>>4), 8x unrolled ----
    int hl = l >> 4;
    const float2* hp2 = (const float2*)hpre;
    float ax = 0.f, ay = 0.f;
    int p = 0;
    for (; p + 8 <= c; p += 8) {
        int   jj[8]; float ww[8];
        #pragma unroll
        for (int u = 0; u < 8; ++u) jj[u] = js[p+u];
        #pragma unroll
        for (int u = 0; u < 8; ++u) ww[u] = lg[hl][p+u];
        #pragma unroll
        for (int u = 0; u < 8; ++u) {
            float2 v = hp2[(size_t)jj[u]*64 + l];
            ax += ww[u]*v.x; ay += ww[u]*v.y;
        }
    }
    for (; p < c; ++p) {
        float wv = lg[hl][p];
        float2 v = hp2[(size_t)js[p]*64 + l];
        ax += wv*v.x; ay += wv*v.y;
    }
    float2 bv = ((const float2*)b1)[l];
    float v0 = ax + bv.x, v1 = ay + bv.y;
    v0 = (v0 > 0.f) ? v0 : expm1f(v0);   // ELU (alpha=1)
    v1 = (v1 > 0.f) ? v1 : expm1f(v1);
    { float2 hw; hw.x = v0; hw.y = v1; *(float2*)(h1s + 2*l) = hw; }
    WFENCE();                          // h1s[] visible across lanes

    // ---- layer-2 pre: h2[o=l] = h1s . W2T[l][:], lane-private float4 row ----
    const float4* wrow = (const float4*)(W2T + (size_t)l*D1);
    float h2 = 0.f;
    #pragma unroll 8
    for (int k4 = 0; k4 < 32; ++k4) {
        float4 wv = wrow[k4];
        float4 hvv = *(const float4*)(h1s + k4*4);   // broadcast LDS read
        h2 += wv.x*hvv.x + wv.y*hvv.y + wv.z*hvv.z + wv.w*hvv.w;
    }
    h2pre[(size_t)i*OUT_DIM + l] = h2;
    float ps = h2 * a_src2[l];
    float pd = h2 * a_dst2[l];
    #pragma unroll
    for (int off = 32; off >= 1; off >>= 1) {
        ps += __shfl_xor(ps, off, 64);
        pd += __shfl_xor(pd, off, 64);
    }
    if (l == 0) { es2[i] = ps; ed2[i] = pd; }
}

// ---------------- kC: wave-per-row layer-2 softmax + aggregate ----------------
// grid N/4, block 256, zero __syncthreads. Pre-normalized weights in LDS.
__global__ __launch_bounds__(256, 4) void kC(
    const float* __restrict__ h2pre, const float* __restrict__ es2,
    const float* __restrict__ ed2,   const int* __restrict__ cnt,
    const int* __restrict__ idxg,    const float* __restrict__ b2v,
    float* __restrict__ out)
{
    __shared__ int   jsS[4][MAXNB];
    __shared__ float alS[4][MAXNB];
    int w = threadIdx.x >> 6, l = threadIdx.x & 63;
    int i = blockIdx.x * 4 + w;
    int*   js = jsS[w];
    float* al = alS[w];
    int c = cnt[i];
    float esi = es2[i];

    float l0 = -1e30f, l1 = -1e30f, l2 = -1e30f;
    if (l < c) {
        int j = idxg[i*MAXNB + l];             js[l] = j;
        l0 = lrelu(esi + ed2[j]);
    }
    if (l + 64 < c) {
        int p = l + 64, j = idxg[i*MAXNB + p]; js[p] = j;
        l1 = lrelu(esi + ed2[j]);
    }
    if (l + 128 < c) {
        int p = l + 128, j = idxg[i*MAXNB + p]; js[p] = j;
        l2 = lrelu(esi + ed2[j]);
    }
    float m = fmaxf(l0, fmaxf(l1, l2));
    #pragma unroll
    for (int off = 32; off >= 1; off >>= 1) m = fmaxf(m, __shfl_xor(m, off, 64));
    float e0 = __expf(l0-m), e1 = __expf(l1-m), e2 = __expf(l2-m);
    float s = e0 + e1 + e2;
    #pragma unroll
    for (int off = 32; off >= 1; off >>= 1) s += __shfl_xor(s, off, 64);
    float inv = 1.f / s;
    al[l]     = e0*inv;
    al[l+64]  = e1*inv;
    al[l+128] = e2*inv;
    WFENCE();                          // js/al visible across lanes

    float acc = 0.f;
    int p = 0;
    for (; p + 8 <= c; p += 8) {
        int   jj[8]; float ww[8];
        #pragma unroll
        for (int u = 0; u < 8; ++u) jj[u] = js[p+u];
        #pragma unroll
        for (int u = 0; u < 8; ++u) ww[u] = al[p+u];
        #pragma unroll
        for (int u = 0; u < 8; ++u)
            acc += ww[u] * h2pre[(size_t)jj[u]*OUT_DIM + l];
    }
    for (; p < c; ++p)
        acc += al[p] * h2pre[(size_t)js[p]*OUT_DIM + l];
    out[(size_t)i*OUT_DIM + l] = acc + b2v[l];
}

extern "C" void kernel_launch(void* const* d_in, const int* in_sizes, int n_in,
                              void* d_out, int out_size, void* d_ws, size_t ws_size,
                              hipStream_t stream) {
    const float* x      = (const float*)d_in[0];
    const float* adj    = (const float*)d_in[1];
    const float* W1     = (const float*)d_in[2];
    const float* a_src1 = (const float*)d_in[3];
    const float* a_dst1 = (const float*)d_in[4];
    const float* b1     = (const float*)d_in[5];
    const float* W2     = (const float*)d_in[6];
    const float* a_src2 = (const float*)d_in[7];
    const float* a_dst2 = (const float*)d_in[8];
    const float* b2v    = (const float*)d_in[9];
    float* out = (float*)d_out;

    float* ws    = (float*)d_ws;
    float* hpre  = ws;                         // N*128
    float* h2pre = hpre  + (size_t)N*D1;       // N*64
    float* es1   = h2pre + (size_t)N*OUT_DIM;  // N*4
    float* ed1   = es1   + (size_t)N*HEADS1;   // N*4 (16B-aligned)
    float* es2   = ed1   + (size_t)N*HEADS1;   // N
    float* ed2   = es2   + N;                  // N
    float* W2T   = ed2   + N;                  // 64*128
    int*   cnt   = (int*)(W2T + OUT_DIM*D1);   // N
    int*   idxg  = cnt + N;                    // N*MAXNB

    kA<<<N/4, 256, 0, stream>>>(x, W1, a_src1, a_dst1, W2, hpre, es1, ed1, W2T);
    kB<<<N/4, 256, 0, stream>>>(adj, hpre, es1, ed1, b1, W2T, a_src2, a_dst2,
                                cnt, idxg, h2pre, es2, ed2);
    kC<<<N/4, 256, 0, stream>>>(h2pre, es2, ed2, cnt, idxg, b2v, out);
}